// Round 1
// baseline (308.537 us; speedup 1.0000x reference)
//
#include <hip/hip_runtime.h>
#include <stdint.h>

#define HIDDEN 1024
#define BATCH  4
#define SEQ    2048
#define TOKENS (BATCH * SEQ)      // 8192
#define QKVD   (3 * HIDDEN)       // 3072

typedef unsigned short u16;
typedef __attribute__((ext_vector_type(8))) short   short8;   // 8 bf16 = 4 VGPRs
typedef __attribute__((ext_vector_type(4))) float   floatx4;

// deterministic round-to-nearest-even f32 -> bf16 (no NaN inputs here)
__device__ __forceinline__ u16 f32_bf16_rne(float f) {
    unsigned int u = __float_as_uint(f);
    u += 0x7FFFu + ((u >> 16) & 1u);
    return (u16)(u >> 16);
}

// ---------------------------------------------------------------- convert
__global__ __launch_bounds__(256) void cvt_bf16_kernel(
        const float* __restrict__ src, u16* __restrict__ dst, int n4) {
    int i = blockIdx.x * 256 + threadIdx.x;
    if (i >= n4) return;
    float4 v = ((const float4*)src)[i];
    ushort4 o;
    o.x = f32_bf16_rne(v.x); o.y = f32_bf16_rne(v.y);
    o.z = f32_bf16_rne(v.z); o.w = f32_bf16_rne(v.w);
    ((ushort4*)dst)[i] = o;
}

// ---------------------------------------------------------------- GEMM (NT)
// C[M,N] = A[M,K] * B[N,K]^T.  128x128 block tile, BK=32, 256 threads (4 waves),
// each wave 64x64 via 4x4 grid of 16x16x32 bf16 MFMA. global_load_lds width 16.
// EPI: 0 = bf16 store + bias[col]; 1 = f32 store * scale; 2 = f32 store.
template <int EPI>
__global__ __launch_bounds__(256) void gemm_bt(
        const u16* __restrict__ A, const u16* __restrict__ B,
        void* __restrict__ Cv, const float* __restrict__ bias,
        int K, int lda, int ldb, int ldc,
        size_t sA, size_t sB, size_t sC, float scale) {
    __shared__ u16 As[128 * 32];   // 8 KB, row-major [128][32], K-contiguous
    __shared__ u16 Bs[128 * 32];

    const int t    = threadIdx.x;
    const int lane = t & 63;
    const int wid  = t >> 6;
    const int bm   = blockIdx.y * 128;
    const int bn   = blockIdx.x * 128;

    const u16* Ab = A + (size_t)blockIdx.z * sA;
    const u16* Bb = B + (size_t)blockIdx.z * sB;

    // staging geometry: per wave-issue, lane i -> tile row base+i/4, col (i%4)*8 elems
    const int srow = lane >> 2;          // 0..15
    const int scol = (lane & 3) * 8;     // 0,8,16,24

    // fragment geometry (verified m89/m91 mappings)
    const int wm = (wid >> 1) * 64;
    const int wn = (wid & 1) * 64;
    const int fr = lane & 15;            // row-in-16 of A/B fragment
    const int fk = (lane >> 4) * 8;      // k offset of fragment

    floatx4 acc[4][4];
#pragma unroll
    for (int i = 0; i < 4; i++)
#pragma unroll
        for (int j = 0; j < 4; j++) acc[i][j] = (floatx4){0.f, 0.f, 0.f, 0.f};

    for (int k0 = 0; k0 < K; k0 += 32) {
        __syncthreads();   // previous iter's LDS reads complete before overwrite
#pragma unroll
        for (int j = 0; j < 2; j++) {
            const int rt = (wid * 2 + j) * 16 + srow;           // tile row 0..127
            const u16* ga = Ab + (size_t)(bm + rt) * lda + (k0 + scol);
            __builtin_amdgcn_global_load_lds(
                (const __attribute__((address_space(1))) void*)ga,
                (__attribute__((address_space(3))) void*)(&As[(wid * 2 + j) * 512]),
                16, 0, 0);
            const u16* gb = Bb + (size_t)(bn + rt) * ldb + (k0 + scol);
            __builtin_amdgcn_global_load_lds(
                (const __attribute__((address_space(1))) void*)gb,
                (__attribute__((address_space(3))) void*)(&Bs[(wid * 2 + j) * 512]),
                16, 0, 0);
        }
        __syncthreads();   // compiler drains vmcnt before barrier

        short8 af[4], bf[4];
#pragma unroll
        for (int mi = 0; mi < 4; mi++)
            af[mi] = *(const short8*)&As[(wm + mi * 16 + fr) * 32 + fk];
#pragma unroll
        for (int ni = 0; ni < 4; ni++)
            bf[ni] = *(const short8*)&Bs[(wn + ni * 16 + fr) * 32 + fk];
#pragma unroll
        for (int mi = 0; mi < 4; mi++)
#pragma unroll
            for (int ni = 0; ni < 4; ni++)
                acc[mi][ni] = __builtin_amdgcn_mfma_f32_16x16x32_bf16(
                    af[mi], bf[ni], acc[mi][ni], 0, 0, 0);
    }

    // epilogue: C/D 16x16 mapping col=lane&15, row=(lane>>4)*4+reg
    const int crow0 = bm + wm + (lane >> 4) * 4;
    const int ccol0 = bn + wn + fr;
    const size_t coff = (size_t)blockIdx.z * sC;

    if (EPI == 0) {
        u16* C = (u16*)Cv;
        float bv[4];
#pragma unroll
        for (int ni = 0; ni < 4; ni++) bv[ni] = bias[ccol0 + ni * 16];
#pragma unroll
        for (int mi = 0; mi < 4; mi++)
#pragma unroll
            for (int ni = 0; ni < 4; ni++)
#pragma unroll
                for (int r = 0; r < 4; r++)
                    C[coff + (size_t)(crow0 + mi * 16 + r) * ldc + (ccol0 + ni * 16)] =
                        f32_bf16_rne(acc[mi][ni][r] + bv[ni]);
    } else {
        float* C = (float*)Cv;
#pragma unroll
        for (int mi = 0; mi < 4; mi++)
#pragma unroll
            for (int ni = 0; ni < 4; ni++)
#pragma unroll
                for (int r = 0; r < 4; r++) {
                    float v = acc[mi][ni][r];
                    if (EPI == 1) v *= scale;
                    C[coff + (size_t)(crow0 + mi * 16 + r) * ldc + (ccol0 + ni * 16)] = v;
                }
    }
}

// ---------------------------------------------------------------- softmax
// one block per row; 2048 fp32 scores (already scaled) -> 2048 bf16 probs
__global__ __launch_bounds__(256) void softmax_kernel(
        const float* __restrict__ S, u16* __restrict__ P) {
    __shared__ float redm[4];
    __shared__ float reds[4];
    const size_t base = (size_t)blockIdx.x * SEQ;
    const int t = threadIdx.x, lane = t & 63, wid = t >> 6;
    const float4* src = (const float4*)(S + base);
    float4 a = src[t], b = src[t + 256];

    float m = fmaxf(fmaxf(fmaxf(a.x, a.y), fmaxf(a.z, a.w)),
                    fmaxf(fmaxf(b.x, b.y), fmaxf(b.z, b.w)));
#pragma unroll
    for (int off = 32; off; off >>= 1) m = fmaxf(m, __shfl_xor(m, off, 64));
    if (lane == 0) redm[wid] = m;
    __syncthreads();
    m = fmaxf(fmaxf(redm[0], redm[1]), fmaxf(redm[2], redm[3]));

    float e[8];
    e[0] = __expf(a.x - m); e[1] = __expf(a.y - m);
    e[2] = __expf(a.z - m); e[3] = __expf(a.w - m);
    e[4] = __expf(b.x - m); e[5] = __expf(b.y - m);
    e[6] = __expf(b.z - m); e[7] = __expf(b.w - m);
    float s = e[0] + e[1] + e[2] + e[3] + e[4] + e[5] + e[6] + e[7];
#pragma unroll
    for (int off = 32; off; off >>= 1) s += __shfl_xor(s, off, 64);
    if (lane == 0) reds[wid] = s;
    __syncthreads();
    s = reds[0] + reds[1] + reds[2] + reds[3];
    const float r = 1.f / s;

    ushort4* dst = (ushort4*)(P + base);
    ushort4 o0, o1;
    o0.x = f32_bf16_rne(e[0] * r); o0.y = f32_bf16_rne(e[1] * r);
    o0.z = f32_bf16_rne(e[2] * r); o0.w = f32_bf16_rne(e[3] * r);
    o1.x = f32_bf16_rne(e[4] * r); o1.y = f32_bf16_rne(e[5] * r);
    o1.z = f32_bf16_rne(e[6] * r); o1.w = f32_bf16_rne(e[7] * r);
    dst[t] = o0;
    dst[t + 256] = o1;
}

// ---------------------------------------------------------------- V transpose
// Vt[b][h][s] <- qkv[b*SEQ+s][2*HIDDEN+h], 64x64 LDS tiles, pad 66 (bank-safe)
__global__ __launch_bounds__(256) void transposeV_kernel(
        const u16* __restrict__ qkv, u16* __restrict__ Vt) {
    __shared__ u16 tile[64][66];
    const int b = blockIdx.z;
    const int s0 = blockIdx.x * 64, h0 = blockIdx.y * 64;
    const int t = threadIdx.x;
    const int c = t & 63, r4 = t >> 6;
#pragma unroll
    for (int i = 0; i < 16; i++) {
        int sl = i * 4 + r4;
        tile[sl][c] = qkv[(size_t)(b * SEQ + s0 + sl) * QKVD + 2 * HIDDEN + h0 + c];
    }
    __syncthreads();
#pragma unroll
    for (int i = 0; i < 16; i++) {
        int hl = i * 4 + r4;
        Vt[(size_t)(b * HIDDEN + h0 + hl) * SEQ + s0 + c] = tile[c][hl];
    }
}

// ---------------------------------------------------------------- launch
extern "C" void kernel_launch(void* const* d_in, const int* in_sizes, int n_in,
                              void* d_out, int out_size, void* d_ws, size_t ws_size,
                              hipStream_t stream) {
    const float* x    = (const float*)d_in[0];   // [4,2048,1024]
    const float* W    = (const float*)d_in[1];   // [3072,1024]
    const float* bias = (const float*)d_in[2];   // [3072]
    float* out = (float*)d_out;                  // [4,2048,1024]

    // workspace layout (191 MB total)
    u16* Xb  = (u16*)d_ws;                                  // 8192x1024 bf16
    u16* Wb  = Xb + (size_t)TOKENS * HIDDEN;                // 3072x1024 bf16
    u16* qkv = Wb + (size_t)QKVD * HIDDEN;                  // 8192x3072 bf16
    float* scores = (float*)(qkv + (size_t)TOKENS * QKVD);  // 4x2048x2048 f32
    u16* P  = (u16*)(scores + (size_t)BATCH * SEQ * SEQ);   // 4x2048x2048 bf16
    u16* Vt = P + (size_t)BATCH * SEQ * SEQ;                // 4x1024x2048 bf16

    // 1) fp32 -> bf16 casts
    cvt_bf16_kernel<<<TOKENS * HIDDEN / 4 / 256, 256, 0, stream>>>(x, Xb, TOKENS * HIDDEN / 4);
    cvt_bf16_kernel<<<QKVD * HIDDEN / 4 / 256, 256, 0, stream>>>(W, Wb, QKVD * HIDDEN / 4);

    // 2) QKV projection: qkv = Xb @ Wb^T + bias  (bf16 out)
    gemm_bt<0><<<dim3(QKVD / 128, TOKENS / 128, 1), 256, 0, stream>>>(
        Xb, Wb, qkv, bias, HIDDEN, HIDDEN, HIDDEN, QKVD, 0, 0, 0, 1.f);

    // 3) scores = scale * Q @ K^T per batch (f32 out)
    gemm_bt<1><<<dim3(SEQ / 128, SEQ / 128, BATCH), 256, 0, stream>>>(
        qkv, qkv + HIDDEN, scores, nullptr, HIDDEN, QKVD, QKVD, SEQ,
        (size_t)SEQ * QKVD, (size_t)SEQ * QKVD, (size_t)SEQ * SEQ, 0.03125f);

    // 4) row softmax -> bf16 P
    softmax_kernel<<<BATCH * SEQ, 256, 0, stream>>>(scores, P);

    // 5) V transpose (bias already folded in step 2)
    transposeV_kernel<<<dim3(SEQ / 64, HIDDEN / 64, BATCH), 256, 0, stream>>>(qkv, Vt);

    // 6) out = P @ Vt^T per batch (f32 out)
    gemm_bt<2><<<dim3(HIDDEN / 128, SEQ / 128, BATCH), 256, 0, stream>>>(
        P, Vt, out, nullptr, SEQ, SEQ, SEQ, HIDDEN,
        (size_t)SEQ * SEQ, (size_t)HIDDEN * SEQ, (size_t)SEQ * HIDDEN, 1.f);
}